// Round 3
// baseline (221.309 us; speedup 1.0000x reference)
//
#include <hip/hip_runtime.h>
#include <hip/hip_bf16.h>

#define B 16
#define N 1024
#define F_IN 64
#define H 256
#define ALPHA 0.2f
#define LOG2E 1.44269504f

typedef __attribute__((ext_vector_type(8))) _Float16 half8;
typedef __attribute__((ext_vector_type(4))) _Float16 half4;
typedef __attribute__((ext_vector_type(4))) float floatx4;
typedef __attribute__((ext_vector_type(16))) float floatx16;

#if __has_builtin(__builtin_amdgcn_exp2f)
#define EXP2F(x) __builtin_amdgcn_exp2f(x)
#else
#define EXP2F(x) exp2f(x)
#endif

__device__ __forceinline__ floatx4 mfma_f16(half8 a, half8 b, floatx4 c) {
    return __builtin_amdgcn_mfma_f32_16x16x32_f16(a, b, c, 0, 0, 0);
}
__device__ __forceinline__ floatx16 mfma32_f16(half8 a, half8 b, floatx16 c) {
    return __builtin_amdgcn_mfma_f32_32x32x16_f16(a, b, c, 0, 0, 0);
}

// ---------------------------------------------------------------------------
// Fused front kernel:
//   blocks [0,1024):    adj -> bitmask, plane-packed words
//   blocks [1024,1536): embed -> f16 x
//   blocks [1536,1570): W -> B-frag f16 (32) ; wa = W@a (2)
// mask32[(b*N+i)*32 + jt], bit ((j&3)*8 + (j>>2)) within the 32-j word
__global__ __launch_bounds__(256) void k_front(const float* __restrict__ adj,
                                               const float* __restrict__ nf,
                                               const float* __restrict__ embW,
                                               const float* __restrict__ embB,
                                               const float* __restrict__ W0, const float* __restrict__ W1,
                                               const float* __restrict__ a10, const float* __restrict__ a20,
                                               const float* __restrict__ a11, const float* __restrict__ a21,
                                               unsigned* __restrict__ mask32,
                                               _Float16* __restrict__ xf,
                                               _Float16* __restrict__ wBf,
                                               float* __restrict__ wa1, float* __restrict__ wa2) {
    __shared__ float lds[256 * 17];
    const int blk = blockIdx.x;
    const int t = threadIdx.x;
    const int lane = t & 63;

    if (blk < 1024) {
        const int wv = blk * 4 + (t >> 6);
#pragma unroll 2
        for (int task = wv; task < B * N * 4; task += 4096) {
            const float4 v = *(const float4*)(adj + (size_t)task * 256 + lane * 4);
            unsigned long long b0 = __ballot(v.x > 0.f);
            unsigned long long b1 = __ballot(v.y > 0.f);
            unsigned long long b2 = __ballot(v.z > 0.f);
            unsigned long long b3 = __ballot(v.w > 0.f);
            if (lane < 8) {
                unsigned w0 = (unsigned)((b0 >> (8 * lane)) & 0xff)
                            | ((unsigned)((b1 >> (8 * lane)) & 0xff) << 8)
                            | ((unsigned)((b2 >> (8 * lane)) & 0xff) << 16)
                            | ((unsigned)((b3 >> (8 * lane)) & 0xff) << 24);
                const int jg = task & 3, row = task >> 2;
                mask32[(size_t)row * 32 + jg * 8 + lane] = w0;
            }
        }
        return;
    }
    if (blk < 1536) {
        const int row0 = (blk - 1024) * 32;
        float* nfs = lds;                       // [f][32]
        for (int idx = t; idx < 32 * F_IN; idx += 256) {
            int r = idx >> 6, f = idx & 63;
            nfs[f * 32 + r] = nf[(size_t)(row0 + r) * F_IN + f];
        }
        __syncthreads();
        const int c = t;
        float acc[32];
        const float bv = embB[c];
#pragma unroll
        for (int r = 0; r < 32; r++) acc[r] = bv;
#pragma unroll 8
        for (int f = 0; f < F_IN; f++) {
            const float w = embW[f * H + c];
            const float* nrow = nfs + f * 32;
#pragma unroll
            for (int q = 0; q < 8; q++) {
                float4 n4 = *(const float4*)(nrow + q * 4);
                acc[q * 4 + 0] += n4.x * w;
                acc[q * 4 + 1] += n4.y * w;
                acc[q * 4 + 2] += n4.z * w;
                acc[q * 4 + 3] += n4.w * w;
            }
        }
#pragma unroll
        for (int r = 0; r < 32; r++)
            xf[(size_t)(row0 + r) * H + c] = (_Float16)acc[r];
        return;
    }
    const int pb = blk - 1536;
    if (pb >= 32) {
        const int l = pb - 32;
        const float* W = l ? W1 : W0;
        const float* a1 = l ? a11 : a10;
        const float* a2 = l ? a21 : a20;
        float* a1s = lds;
        float* a2s = lds + 256;
        a1s[t] = a1[t]; a2s[t] = a2[t];
        __syncthreads();
        float v1 = 0.f, v2 = 0.f;
        for (int c = 0; c < H; c += 4) {
            float4 w = *(const float4*)&W[t * H + c];
            v1 += w.x * a1s[c] + w.y * a1s[c + 1] + w.z * a1s[c + 2] + w.w * a1s[c + 3];
            v2 += w.x * a2s[c] + w.y * a2s[c + 1] + w.z * a2s[c + 2] + w.w * a2s[c + 3];
        }
        wa1[l * H + t] = v1;
        wa2[l * H + t] = v2;
        return;
    }
    const int l = pb >> 4, ct = pb & 15;
    const float* W = l ? W1 : W0;
#pragma unroll
    for (int rep = 0; rep < 16; rep++) {
        int idx = rep * 256 + t;
        int k = idx >> 4, cl = idx & 15;
        lds[k * 17 + cl] = W[k * H + ct * 16 + cl];
    }
    __syncthreads();
    const int w = t >> 6;
    const int l15 = lane & 15, quad = lane >> 4;
#pragma unroll
    for (int e = 0; e < 2; e++) {
        const int ks = w * 2 + e;
        half8 bf;
#pragma unroll
        for (int jj = 0; jj < 8; jj++)
            bf[jj] = (_Float16)lds[(ks * 32 + quad * 8 + jj) * 17 + l15];
        *(half8*)(wBf + (size_t)(((l * 16 + ct) * 8 + ks) * 64 + lane) * 8) = bf;
    }
}

// ---------------------------------------------------------------------------
// h = x @ W (pure f16 MFMA, 16x16x32 internally). x staged to LDS in A-frag
// order (1 barrier), W read as coalesced f16 B-frags. h -> hB now written in
// 32x32x16 B-frag order for k_gat: frag (b, ct32(8), jt(32), ks(2)); lane l
// holds col = ct32*32 + (l&31), j = jt*32 + ks*16 + (l>>5)*8 + e.
#define XS(it, ks) ((((it) * 8 + (ks))) * 520)
__global__ __launch_bounds__(256, 4) void k_gemm(const _Float16* __restrict__ xf,
                                                 const _Float16* __restrict__ wBf,
                                                 const float* __restrict__ wa1, const float* __restrict__ wa2,
                                                 _Float16* __restrict__ hB,
                                                 float* __restrict__ s1, float* __restrict__ s2) {
    __shared__ __align__(16) _Float16 sm[8320];
    const int lin = blockIdx.x;
    const int rc = lin >> 1, chalf = lin & 1;
    const int row0 = rc * 32;
    const int t = threadIdx.x;
    const int lane = t & 63, w = t >> 6;
    const int l15 = lane & 15, quad = lane >> 4;

#pragma unroll
    for (int pass = 0; pass < 4; pass++) {
        int idx = pass * 256 + t;
        int row_l = idx >> 5, k8 = idx & 31;
        half8 v = *(const half8*)(xf + (size_t)(row0 + row_l) * H + k8 * 8);
        int it = row_l >> 4, lf = row_l & 15, ks = k8 >> 2, qd = k8 & 3;
        *(half8*)(sm + XS(it, ks) + (qd * 16 + lf) * 8) = v;
    }
    __syncthreads();

    const int ct0 = chalf * 8 + 2 * w;
    const _Float16* pB0 = wBf + (size_t)((ct0 * 8) * 64 + lane) * 8;
    const _Float16* pB1 = wBf + (size_t)(((ct0 + 1) * 8) * 64 + lane) * 8;

    floatx4 acc[2][2];
    floatx4 z = {0.f, 0.f, 0.f, 0.f};
    acc[0][0] = z; acc[0][1] = z; acc[1][0] = z; acc[1][1] = z;
    float sp1a = 0.f, sp2a = 0.f, sp1b = 0.f, sp2b = 0.f;

    half8 B0 = *(const half8*)(pB0);
    half8 B1 = *(const half8*)(pB1);

#pragma unroll
    for (int ks = 0; ks < 8; ks++) {
        half8 nB0 = B0, nB1 = B1;
        if (ks < 7) {
            const int o = (ks + 1) * 512;
            nB0 = *(const half8*)(pB0 + o);
            nB1 = *(const half8*)(pB1 + o);
        }
        half8 A0 = *(const half8*)(sm + XS(0, ks) + lane * 8);
        half8 A1 = *(const half8*)(sm + XS(1, ks) + lane * 8);
        acc[0][0] = mfma_f16(A0, B0, acc[0][0]);
        acc[0][1] = mfma_f16(A0, B1, acc[0][1]);
        acc[1][0] = mfma_f16(A1, B0, acc[1][0]);
        acc[1][1] = mfma_f16(A1, B1, acc[1][1]);
        if (chalf == 0 && w == 0) {
            float4 w1a = *(const float4*)(wa1 + ks * 32 + quad * 8);
            float4 w1b = *(const float4*)(wa1 + ks * 32 + quad * 8 + 4);
            float4 w2a = *(const float4*)(wa2 + ks * 32 + quad * 8);
            float4 w2b = *(const float4*)(wa2 + ks * 32 + quad * 8 + 4);
            float wv1[8] = {w1a.x, w1a.y, w1a.z, w1a.w, w1b.x, w1b.y, w1b.z, w1b.w};
            float wv2[8] = {w2a.x, w2a.y, w2a.z, w2a.w, w2b.x, w2b.y, w2b.z, w2b.w};
#pragma unroll
            for (int j = 0; j < 8; j++) {
                float xa = (float)A0[j];
                float xb = (float)A1[j];
                sp1a += xa * wv1[j]; sp2a += xa * wv2[j];
                sp1b += xb * wv1[j]; sp2b += xb * wv2[j];
            }
        }
        B0 = nB0; B1 = nB1;
    }

    __syncthreads();
    _Float16* trc = sm;                         // [c_local(128)][40]
#pragma unroll
    for (int rg = 0; rg < 2; rg++) {
#pragma unroll
        for (int n2 = 0; n2 < 2; n2++) {
            const int c_l = (2 * w + n2) * 16 + l15;
            half4 hv;
            hv[0] = (_Float16)acc[rg][n2][0];
            hv[1] = (_Float16)acc[rg][n2][1];
            hv[2] = (_Float16)acc[rg][n2][2];
            hv[3] = (_Float16)acc[rg][n2][3];
            *(half4*)(trc + c_l * 40 + rg * 16 + quad * 4) = hv;
        }
    }
    __syncthreads();
    {
        // write-out in 32x32x16 B-frag order
        const int bb = row0 >> 10, jtb = (row0 >> 5) & 31;
#pragma unroll
        for (int rep = 0; rep < 2; rep++) {
            int slot = rep * 256 + t;
            int l = slot & 63, frag = slot >> 6;   // frag 0..7
            int k4 = frag >> 1, ks = frag & 1;
            int c_l = k4 * 32 + (l & 31);
            int roff = ks * 16 + (l >> 5) * 8;
            half8 hv = *(const half8*)(trc + c_l * 40 + roff);
            _Float16* dst = hB + ((size_t)((bb * 8 + chalf * 4 + k4) * 32 + jtb) * 2 + ks) * 512 + l * 8;
            *(half8*)dst = hv;
        }
    }
    if (chalf == 0 && w == 0) {
        sp1a += __shfl_xor(sp1a, 16); sp1a += __shfl_xor(sp1a, 32);
        sp2a += __shfl_xor(sp2a, 16); sp2a += __shfl_xor(sp2a, 32);
        sp1b += __shfl_xor(sp1b, 16); sp1b += __shfl_xor(sp1b, 32);
        sp2b += __shfl_xor(sp2b, 16); sp2b += __shfl_xor(sp2b, 32);
        if (quad == 0) {
            s1[row0 + l15] = sp1a; s2[row0 + l15] = sp2a;
            s1[row0 + 16 + l15] = sp1b; s2[row0 + 16 + l15] = sp2b;
        }
    }
}

// ---------------------------------------------------------------------------
// Fused GAT, 32x32x16 MFMA: 256 blocks; each block = 128 rows x 128 cols
// (chalf). Wave w owns rows w*32..+31 (one 32-row A-frag, generated once —
// no P duplication) x 4 ct32-tiles. Per-row B-fragment bytes halved vs the
// 16x16 structure. Row-sum l via 2 ones-MFMAs/jt (accl has same reg->row
// map as acc). P in exp2 domain with folded per-row constants.
template <int LAST>
__global__ __launch_bounds__(256, 1) void k_gat(const _Float16* __restrict__ hB,
                                                const float* __restrict__ s1g,
                                                const float* __restrict__ s2g,
                                                const unsigned* __restrict__ mask32,
                                                float* __restrict__ outf,
                                                _Float16* __restrict__ oxf,
                                                float* __restrict__ psum, float* __restrict__ pmax) {
    __shared__ float s2s[N];
    __shared__ unsigned msk[128][33];
    __shared__ float wmax[4];
    __shared__ float red1[4][128];
    __shared__ float red2[4][128];
    const int lin = blockIdx.x;                     // 256 blocks
    const int xcd = lin & 7, sl = lin >> 3;         // sl 0..31
    const int b = xcd * 2 + (sl & 1);               // batch pinned to XCD pair
    const int chunk = (sl >> 1) & 7;                // 8 chunks of 128 rows
    const int chalf = sl >> 4;
    const int i0 = chunk * 128;
    const int t = threadIdx.x;
    const int lane = t & 63, w = t >> 6;            // wave w = 32-row group
    const int l31 = lane & 31, hi = lane >> 5;
    const int hi2 = hi * 2, hi8 = hi * 8;

    // ---- stage s2*log2e + mask rows; block-local s2max (scaled domain) ----
    float tm = -INFINITY;
    for (int idx = t; idx < N; idx += 256) {
        float v = s2g[b * N + idx] * LOG2E;
        s2s[idx] = v;
        tm = fmaxf(tm, v);
    }
#pragma unroll
    for (int off = 1; off <= 32; off <<= 1) tm = fmaxf(tm, __shfl_xor(tm, off));
    if (lane == 0) wmax[w] = tm;
#pragma unroll
    for (int pass = 0; pass < 16; pass++) {
        int idx = pass * 256 + t;
        int r = idx >> 5, wd = idx & 31;
        msk[r][wd] = mask32[(size_t)(b * N + i0 + r) * 32 + wd];
    }
    __syncthreads();
    const float s2maxL = fmaxf(fmaxf(wmax[0], wmax[1]), fmaxf(wmax[2], wmax[3]));

    // per-row folded constants: exponent = max(a1c + s2L, fma(ALPHA, s2L, a2c))
    const float s1L = s1g[b * N + i0 + w * 32 + l31] * LOG2E;
    const float tmx = s1L + s2maxL;
    const float mL = fmaxf(tmx, ALPHA * tmx);
    const float a1c = s1L - mL;
    const float a2c = fmaf(ALPHA, s1L, -mL);

    // B-frag pointers: frag (b, ct32 = chalf*4+k4, jt, ks); per-jt stride 1024 halves
    const _Float16* pb[4][2];
#pragma unroll
    for (int k4 = 0; k4 < 4; k4++)
#pragma unroll
        for (int ks = 0; ks < 2; ks++)
            pb[k4][ks] = hB + ((size_t)(b * 8 + chalf * 4 + k4) * 64 + ks) * 512 + lane * 8;

    floatx16 acc[4];
    floatx16 accl;
#pragma unroll
    for (int r = 0; r < 16; r++) accl[r] = 0.f;
#pragma unroll
    for (int k4 = 0; k4 < 4; k4++) acc[k4] = accl;

    half8 ones;
#pragma unroll
    for (int jj = 0; jj < 8; jj++) ones[jj] = (_Float16)1.0f;

    const float* svp = s2s + hi8;
    const unsigned* mr = &msk[w * 32 + l31][0];

    half8 bufA[4][2], bufB[4][2];
#pragma unroll
    for (int k4 = 0; k4 < 4; k4++) {
        bufA[k4][0] = *(const half8*)(pb[k4][0]);
        bufA[k4][1] = *(const half8*)(pb[k4][1]);
    }

#define GAT_STEP(JT, BUF)                                                      \
    do {                                                                       \
        const unsigned m = mr[JT];                                             \
        float4 sa0 = *(const float4*)(svp + (JT) * 32);                        \
        float4 sb0 = *(const float4*)(svp + (JT) * 32 + 4);                    \
        float4 sa1 = *(const float4*)(svp + (JT) * 32 + 16);                   \
        float4 sb1 = *(const float4*)(svp + (JT) * 32 + 20);                   \
        float sv0[8] = {sa0.x, sa0.y, sa0.z, sa0.w, sb0.x, sb0.y, sb0.z, sb0.w};\
        float sv1[8] = {sa1.x, sa1.y, sa1.z, sa1.w, sb1.x, sb1.y, sb1.z, sb1.w};\
        unsigned mq0 = m >> hi2;                                               \
        unsigned mq1 = m >> (4 + hi2);                                         \
        union { _Float16 h[8]; half8 v; } pk0, pk1;                            \
        _Pragma("unroll")                                                      \
        for (int e = 0; e < 8; e++) {                                          \
            const int bp = (e & 3) * 8 + (e >> 2);                             \
            float u0 = a1c + sv0[e];                                           \
            float v0 = fmaf(ALPHA, sv0[e], a2c);                               \
            float w0 = fmaxf(u0, v0);                                          \
            w0 = ((mq0 >> bp) & 1u) ? w0 : -126.f;                             \
            pk0.h[e] = (_Float16)EXP2F(w0);                                    \
            float u1 = a1c + sv1[e];                                           \
            float v1 = fmaf(ALPHA, sv1[e], a2c);                               \
            float w1 = fmaxf(u1, v1);                                          \
            w1 = ((mq1 >> bp) & 1u) ? w1 : -126.f;                             \
            pk1.h[e] = (_Float16)EXP2F(w1);                                    \
        }                                                                      \
        accl = mfma32_f16(pk0.v, ones, accl);                                  \
        _Pragma("unroll")                                                      \
        for (int k4 = 0; k4 < 4; k4++) acc[k4] = mfma32_f16(pk0.v, BUF[k4][0], acc[k4]); \
        accl = mfma32_f16(pk1.v, ones, accl);                                  \
        _Pragma("unroll")                                                      \
        for (int k4 = 0; k4 < 4; k4++) acc[k4] = mfma32_f16(pk1.v, BUF[k4][1], acc[k4]); \
    } while (0)

    for (int jt = 0; jt < 32; jt += 2) {
        {
            const int o = (jt + 1) * 1024;
#pragma unroll
            for (int k4 = 0; k4 < 4; k4++) {
                bufB[k4][0] = *(const half8*)(pb[k4][0] + o);
                bufB[k4][1] = *(const half8*)(pb[k4][1] + o);
            }
        }
        GAT_STEP(jt, bufA);
        if (jt + 2 < 32) {
            const int o = (jt + 2) * 1024;
#pragma unroll
            for (int k4 = 0; k4 < 4; k4++) {
                bufA[k4][0] = *(const half8*)(pb[k4][0] + o);
                bufA[k4][1] = *(const half8*)(pb[k4][1] + o);
            }
        }
        GAT_STEP(jt + 1, bufB);
    }
#undef GAT_STEP

    // accl[reg] = row sum for row (reg&3)+8*(reg>>2)+4*hi — same map as acc
    float invv[16];
#pragma unroll
    for (int r = 0; r < 16; r++) invv[r] = 1.f / accl[r];

    const size_t rowb = (size_t)b * N + i0 + w * 32 + 4 * hi;
    const int colbase = chalf * 128;
#pragma unroll
    for (int k4 = 0; k4 < 4; k4++) {
        const int c = colbase + k4 * 32 + l31;
        float cs = 0.f, cm = -INFINITY;
#pragma unroll
        for (int reg = 0; reg < 16; reg++) {
            const int roff = (reg & 3) + 8 * (reg >> 2);
            float v = fmaxf(acc[k4][reg] * invv[reg], 0.f);
            if (LAST) {
                outf[(rowb + roff) * H + c] = v;
                cs += v; cm = fmaxf(cm, v);
            } else {
                oxf[(rowb + roff) * H + c] = (_Float16)v;
            }
        }
        if (LAST) {
            cs += __shfl_xor(cs, 32);
            cm = fmaxf(cm, __shfl_xor(cm, 32));
            if (hi == 0) { red1[w][k4 * 32 + l31] = cs; red2[w][k4 * 32 + l31] = cm; }
        }
    }
    if (LAST) {
        __syncthreads();
        if (t < 128) {
            float s = red1[0][t] + red1[1][t] + red1[2][t] + red1[3][t];
            float m = fmaxf(fmaxf(red2[0][t], red2[1][t]), fmaxf(red2[2][t], red2[3][t]));
            psum[(b * 8 + chunk) * H + chalf * 128 + t] = s;
            pmax[(b * 8 + chunk) * H + chalf * 128 + t] = m;
        }
    }
}

// ---------------------------------------------------------------------------
// finish mean+max over 8 chunk-partials, then 2-layer MLP -> g[b,:]
__global__ __launch_bounds__(256) void k_pool2(const float* __restrict__ psum,
                                               const float* __restrict__ pmax,
                                               const float* __restrict__ W1, const float* __restrict__ b1,
                                               const float* __restrict__ W2, const float* __restrict__ b2,
                                               float* __restrict__ gout) {
    __shared__ float g_s[H];
    __shared__ float t_s[H];
    const int b = blockIdx.x;
    const int c = threadIdx.x;
    float s = 0.f, m = -INFINITY;
#pragma unroll
    for (int ch = 0; ch < 8; ch++) {
        s += psum[(b * 8 + ch) * H + c];
        m = fmaxf(m, pmax[(b * 8 + ch) * H + c]);
    }
    g_s[c] = s * (1.f / N) + m;
    __syncthreads();
    float a = b1[c];
#pragma unroll 16
    for (int k = 0; k < H; k++) a += g_s[k] * W1[k * H + c];
    t_s[c] = fmaxf(a, 0.f);
    __syncthreads();
    float o = b2[c];
#pragma unroll 16
    for (int k = 0; k < H; k++) o += t_s[k] * W2[k * H + c];
    gout[b * H + c] = o;
}

// ---------------------------------------------------------------------------
extern "C" void kernel_launch(void* const* d_in, const int* in_sizes, int n_in,
                              void* d_out, int out_size, void* d_ws, size_t ws_size,
                              hipStream_t stream) {
    const float* nf    = (const float*)d_in[0];
    const float* adj   = (const float*)d_in[1];
    const float* emb_W = (const float*)d_in[2];
    const float* emb_b = (const float*)d_in[3];
    const float* W0    = (const float*)d_in[4];
    const float* a1_0  = (const float*)d_in[5];
    const float* a2_0  = (const float*)d_in[6];
    const float* W1    = (const float*)d_in[7];
    const float* a1_1  = (const float*)d_in[8];
    const float* a2_1  = (const float*)d_in[9];
    const float* gpW1  = (const float*)d_in[10];
    const float* gpb1  = (const float*)d_in[11];
    const float* gpW2  = (const float*)d_in[12];
    const float* gpb2  = (const float*)d_in[13];

    float* xout = (float*)d_out;
    float* gout = xout + B * N * H;

    char* w = (char*)d_ws;
    _Float16* xf     = (_Float16*)(w);                //  8 MB
    _Float16* hB     = (_Float16*)(w + 8388608);      //  8 MB (32x32 B-frag order)
    unsigned* mask32 = (unsigned*)(w + 16777216);     //  2 MB (plane-packed)
    float* s1        = (float*)(w + 18874368);        // 64 KB
    float* s2        = (float*)(w + 18939904);        // 64 KB
    _Float16* wBf    = (_Float16*)(w + 19005440);     // 256 KB (B-frag, 2 layers)
    float* wa1       = (float*)(w + 19267584);
    float* wa2       = (float*)(w + 19269632);
    float* psum      = (float*)(w + 19271680);        // 128 KB
    float* pmax      = (float*)(w + 19533824);        // 128 KB

    k_front<<<1570, 256, 0, stream>>>(adj, nf, emb_W, emb_b, W0, W1,
                                      a1_0, a2_0, a1_1, a2_1,
                                      mask32, xf, wBf, wa1, wa2);

    // layer 0
    k_gemm<<<1024, 256, 0, stream>>>(xf, wBf, wa1, wa2, hB, s1, s2);
    k_gat<0><<<256, 256, 0, stream>>>(hB, s1, s2, mask32, nullptr, xf,
                                      nullptr, nullptr);

    // layer 1
    k_gemm<<<1024, 256, 0, stream>>>(xf, wBf + 65536, wa1 + H, wa2 + H, hB, s1, s2);
    k_gat<1><<<256, 256, 0, stream>>>(hB, s1, s2, mask32, xout, nullptr,
                                      psum, pmax);

    // pooling MLP
    k_pool2<<<B, 256, 0, stream>>>(psum, pmax, gpW1, gpb1, gpW2, gpb2, gout);
}

// Round 4
// 218.815 us; speedup vs baseline: 1.0114x; 1.0114x over previous
//
#include <hip/hip_runtime.h>
#include <hip/hip_bf16.h>

#define B 16
#define N 1024
#define F_IN 64
#define H 256
#define ALPHA 0.2f
#define LOG2E 1.44269504f

typedef __attribute__((ext_vector_type(8))) _Float16 half8;
typedef __attribute__((ext_vector_type(4))) _Float16 half4;
typedef __attribute__((ext_vector_type(4))) float floatx4;
typedef __attribute__((ext_vector_type(16))) float floatx16;

#if __has_builtin(__builtin_amdgcn_exp2f)
#define EXP2F(x) __builtin_amdgcn_exp2f(x)
#else
#define EXP2F(x) exp2f(x)
#endif

__device__ __forceinline__ floatx4 mfma_f16(half8 a, half8 b, floatx4 c) {
    return __builtin_amdgcn_mfma_f32_16x16x32_f16(a, b, c, 0, 0, 0);
}
__device__ __forceinline__ floatx16 mfma32_f16(half8 a, half8 b, floatx16 c) {
    return __builtin_amdgcn_mfma_f32_32x32x16_f16(a, b, c, 0, 0, 0);
}

// ---------------------------------------------------------------------------
// Fused front kernel:
//   blocks [0,1024):    adj -> bitmask, plane-packed words
//   blocks [1024,1056): W -> B-frag f16 (32)
//   blocks 1056,1057:   wa = W@a
//   block  1058:        embW -> B-frag f16 (K=64, 2 ks slots)
// mask32[(b*N+i)*32 + jt], bit ((j&3)*8 + (j>>2)) within the 32-j word
__global__ __launch_bounds__(256) void k_front(const float* __restrict__ adj,
                                               const float* __restrict__ embW,
                                               const float* __restrict__ W0, const float* __restrict__ W1,
                                               const float* __restrict__ a10, const float* __restrict__ a20,
                                               const float* __restrict__ a11, const float* __restrict__ a21,
                                               unsigned* __restrict__ mask32,
                                               _Float16* __restrict__ wBf,
                                               _Float16* __restrict__ embf,
                                               float* __restrict__ wa1, float* __restrict__ wa2) {
    __shared__ float lds[256 * 17];
    const int blk = blockIdx.x;
    const int t = threadIdx.x;
    const int lane = t & 63;

    if (blk < 1024) {
        const int wv = blk * 4 + (t >> 6);
#pragma unroll 2
        for (int task = wv; task < B * N * 4; task += 4096) {
            const float4 v = *(const float4*)(adj + (size_t)task * 256 + lane * 4);
            unsigned long long b0 = __ballot(v.x > 0.f);
            unsigned long long b1 = __ballot(v.y > 0.f);
            unsigned long long b2 = __ballot(v.z > 0.f);
            unsigned long long b3 = __ballot(v.w > 0.f);
            if (lane < 8) {
                unsigned w0 = (unsigned)((b0 >> (8 * lane)) & 0xff)
                            | ((unsigned)((b1 >> (8 * lane)) & 0xff) << 8)
                            | ((unsigned)((b2 >> (8 * lane)) & 0xff) << 16)
                            | ((unsigned)((b3 >> (8 * lane)) & 0xff) << 24);
                const int jg = task & 3, row = task >> 2;
                mask32[(size_t)row * 32 + jg * 8 + lane] = w0;
            }
        }
        return;
    }
    const int pb = blk - 1024;
    if (pb == 34) {
        // embW [F_IN][H] -> f16 B-frags: slot (ct*2+ks2)*64+lane, reg e =
        // embW[ks2*32 + (lane>>4)*8 + e][ct*16 + (lane&15)]
        for (int s = t; s < 2048; s += 256) {
            const int ln = s & 63, ct2 = s >> 6;
            const int ct = ct2 >> 1, ks2 = ct2 & 1;
            const int q = ln >> 4, lw = ln & 15;
            half8 bf;
#pragma unroll
            for (int e = 0; e < 8; e++)
                bf[e] = (_Float16)embW[(ks2 * 32 + q * 8 + e) * H + ct * 16 + lw];
            *(half8*)(embf + (size_t)s * 8) = bf;
        }
        return;
    }
    if (pb >= 32) {
        const int l = pb - 32;
        const float* W = l ? W1 : W0;
        const float* a1 = l ? a11 : a10;
        const float* a2 = l ? a21 : a20;
        float* a1s = lds;
        float* a2s = lds + 256;
        a1s[t] = a1[t]; a2s[t] = a2[t];
        __syncthreads();
        float v1 = 0.f, v2 = 0.f;
        for (int c = 0; c < H; c += 4) {
            float4 w = *(const float4*)&W[t * H + c];
            v1 += w.x * a1s[c] + w.y * a1s[c + 1] + w.z * a1s[c + 2] + w.w * a1s[c + 3];
            v2 += w.x * a2s[c] + w.y * a2s[c + 1] + w.z * a2s[c + 2] + w.w * a2s[c + 3];
        }
        wa1[l * H + t] = v1;
        wa2[l * H + t] = v2;
        return;
    }
    const int l = pb >> 4, ct = pb & 15;
    const float* W = l ? W1 : W0;
#pragma unroll
    for (int rep = 0; rep < 16; rep++) {
        int idx = rep * 256 + t;
        int k = idx >> 4, cl = idx & 15;
        lds[k * 17 + cl] = W[k * H + ct * 16 + cl];
    }
    __syncthreads();
    const int w = t >> 6;
    const int l15 = lane & 15, quad = lane >> 4;
#pragma unroll
    for (int e = 0; e < 2; e++) {
        const int ks = w * 2 + e;
        half8 bf;
#pragma unroll
        for (int jj = 0; jj < 8; jj++)
            bf[jj] = (_Float16)lds[(ks * 32 + quad * 8 + jj) * 17 + l15];
        *(half8*)(wBf + (size_t)(((l * 16 + ct) * 8 + ks) * 64 + lane) * 8) = bf;
    }
}

// ---------------------------------------------------------------------------
// h = x @ W (pure f16 MFMA, 16x16x32 internally).
// EMB=1 (layer 0): x computed IN-KERNEL from nf via chained MFMA
//   (x = f16(nf) @ f16(embW) + b, f32 accum), scattered into the XS LDS
//   A-frag layout -> main loop unchanged. Removes xf round-trip + k_front
//   embed blocks.
// EMB=0 (layer 1): x staged from xf (written by k_gat<0>).
// h -> hB written in 32x32x16 B-frag order for k_gat.
#define XS(it, ks) ((((it) * 8 + (ks))) * 520)
template <int EMB>
__global__ __launch_bounds__(256, 4) void k_gemm(const _Float16* __restrict__ xf,
                                                 const float* __restrict__ nf,
                                                 const _Float16* __restrict__ embf,
                                                 const float* __restrict__ embB,
                                                 const _Float16* __restrict__ wBf,
                                                 const float* __restrict__ wa1, const float* __restrict__ wa2,
                                                 _Float16* __restrict__ hB,
                                                 float* __restrict__ s1, float* __restrict__ s2) {
    __shared__ __align__(16) _Float16 sm[8320];
    const int lin = blockIdx.x;
    const int rc = lin >> 1, chalf = lin & 1;
    const int row0 = rc * 32;
    const int t = threadIdx.x;
    const int lane = t & 63, w = t >> 6;
    const int l15 = lane & 15, quad = lane >> 4;

    if (EMB) {
        // ---- mini-GEMM: x[32][256] = nf[32][64] @ embW + embB ----
        half8 anf[2][2];
#pragma unroll
        for (int it = 0; it < 2; it++)
#pragma unroll
            for (int ks2 = 0; ks2 < 2; ks2++) {
                const float* src = nf + (size_t)(row0 + it * 16 + l15) * F_IN + ks2 * 32 + quad * 8;
                float4 f0 = *(const float4*)(src);
                float4 f1 = *(const float4*)(src + 4);
                half8 a;
                a[0] = (_Float16)f0.x; a[1] = (_Float16)f0.y;
                a[2] = (_Float16)f0.z; a[3] = (_Float16)f0.w;
                a[4] = (_Float16)f1.x; a[5] = (_Float16)f1.y;
                a[6] = (_Float16)f1.z; a[7] = (_Float16)f1.w;
                anf[it][ks2] = a;
            }
#pragma unroll
        for (int ctl = 0; ctl < 4; ctl++) {
            const int ct = w * 4 + ctl;
            half8 be0 = *(const half8*)(embf + (size_t)((ct * 2 + 0) * 64 + lane) * 8);
            half8 be1 = *(const half8*)(embf + (size_t)((ct * 2 + 1) * 64 + lane) * 8);
            const int col = ct * 16 + l15;
            const float bias = embB[col];
            const int ks = col >> 5, qd = (col >> 3) & 3, e = col & 7;
#pragma unroll
            for (int it = 0; it < 2; it++) {
                floatx4 xa = {0.f, 0.f, 0.f, 0.f};
                xa = mfma_f16(anf[it][0], be0, xa);
                xa = mfma_f16(anf[it][1], be1, xa);
#pragma unroll
                for (int r = 0; r < 4; r++)
                    sm[XS(it, ks) + (qd * 16 + quad * 4 + r) * 8 + e] = (_Float16)(xa[r] + bias);
            }
        }
    } else {
#pragma unroll
        for (int pass = 0; pass < 4; pass++) {
            int idx = pass * 256 + t;
            int row_l = idx >> 5, k8 = idx & 31;
            half8 v = *(const half8*)(xf + (size_t)(row0 + row_l) * H + k8 * 8);
            int it = row_l >> 4, lf = row_l & 15, ks = k8 >> 2, qd = k8 & 3;
            *(half8*)(sm + XS(it, ks) + (qd * 16 + lf) * 8) = v;
        }
    }
    __syncthreads();

    const int ct0 = chalf * 8 + 2 * w;
    const _Float16* pB0 = wBf + (size_t)((ct0 * 8) * 64 + lane) * 8;
    const _Float16* pB1 = wBf + (size_t)(((ct0 + 1) * 8) * 64 + lane) * 8;

    floatx4 acc[2][2];
    floatx4 z = {0.f, 0.f, 0.f, 0.f};
    acc[0][0] = z; acc[0][1] = z; acc[1][0] = z; acc[1][1] = z;
    float sp1a = 0.f, sp2a = 0.f, sp1b = 0.f, sp2b = 0.f;

    half8 B0 = *(const half8*)(pB0);
    half8 B1 = *(const half8*)(pB1);

#pragma unroll
    for (int ks = 0; ks < 8; ks++) {
        half8 nB0 = B0, nB1 = B1;
        if (ks < 7) {
            const int o = (ks + 1) * 512;
            nB0 = *(const half8*)(pB0 + o);
            nB1 = *(const half8*)(pB1 + o);
        }
        half8 A0 = *(const half8*)(sm + XS(0, ks) + lane * 8);
        half8 A1 = *(const half8*)(sm + XS(1, ks) + lane * 8);
        acc[0][0] = mfma_f16(A0, B0, acc[0][0]);
        acc[0][1] = mfma_f16(A0, B1, acc[0][1]);
        acc[1][0] = mfma_f16(A1, B0, acc[1][0]);
        acc[1][1] = mfma_f16(A1, B1, acc[1][1]);
        if (chalf == 0 && w == 0) {
            float4 w1a = *(const float4*)(wa1 + ks * 32 + quad * 8);
            float4 w1b = *(const float4*)(wa1 + ks * 32 + quad * 8 + 4);
            float4 w2a = *(const float4*)(wa2 + ks * 32 + quad * 8);
            float4 w2b = *(const float4*)(wa2 + ks * 32 + quad * 8 + 4);
            float wv1[8] = {w1a.x, w1a.y, w1a.z, w1a.w, w1b.x, w1b.y, w1b.z, w1b.w};
            float wv2[8] = {w2a.x, w2a.y, w2a.z, w2a.w, w2b.x, w2b.y, w2b.z, w2b.w};
#pragma unroll
            for (int j = 0; j < 8; j++) {
                float xa = (float)A0[j];
                float xb = (float)A1[j];
                sp1a += xa * wv1[j]; sp2a += xa * wv2[j];
                sp1b += xb * wv1[j]; sp2b += xb * wv2[j];
            }
        }
        B0 = nB0; B1 = nB1;
    }

    __syncthreads();
    _Float16* trc = sm;                         // [c_local(128)][40]
#pragma unroll
    for (int rg = 0; rg < 2; rg++) {
#pragma unroll
        for (int n2 = 0; n2 < 2; n2++) {
            const int c_l = (2 * w + n2) * 16 + l15;
            half4 hv;
            hv[0] = (_Float16)acc[rg][n2][0];
            hv[1] = (_Float16)acc[rg][n2][1];
            hv[2] = (_Float16)acc[rg][n2][2];
            hv[3] = (_Float16)acc[rg][n2][3];
            *(half4*)(trc + c_l * 40 + rg * 16 + quad * 4) = hv;
        }
    }
    __syncthreads();
    {
        // write-out in 32x32x16 B-frag order
        const int bb = row0 >> 10, jtb = (row0 >> 5) & 31;
#pragma unroll
        for (int rep = 0; rep < 2; rep++) {
            int slot = rep * 256 + t;
            int l = slot & 63, frag = slot >> 6;   // frag 0..7
            int k4 = frag >> 1, ks = frag & 1;
            int c_l = k4 * 32 + (l & 31);
            int roff = ks * 16 + (l >> 5) * 8;
            half8 hv = *(const half8*)(trc + c_l * 40 + roff);
            _Float16* dst = hB + ((size_t)((bb * 8 + chalf * 4 + k4) * 32 + jtb) * 2 + ks) * 512 + l * 8;
            *(half8*)dst = hv;
        }
    }
    if (chalf == 0 && w == 0) {
        sp1a += __shfl_xor(sp1a, 16); sp1a += __shfl_xor(sp1a, 32);
        sp2a += __shfl_xor(sp2a, 16); sp2a += __shfl_xor(sp2a, 32);
        sp1b += __shfl_xor(sp1b, 16); sp1b += __shfl_xor(sp1b, 32);
        sp2b += __shfl_xor(sp2b, 16); sp2b += __shfl_xor(sp2b, 32);
        if (quad == 0) {
            s1[row0 + l15] = sp1a; s2[row0 + l15] = sp2a;
            s1[row0 + 16 + l15] = sp1b; s2[row0 + 16 + l15] = sp2b;
        }
    }
}

// ---------------------------------------------------------------------------
// Fused GAT, 32x32x16 MFMA: 256 blocks; each block = 128 rows x 128 cols
// (chalf). Wave w owns rows w*32..+31 (one 32-row A-frag, generated once —
// no P duplication) x 4 ct32-tiles. Row-sum l via 2 ones-MFMAs/jt (accl has
// same reg->row map as acc). P in exp2 domain with folded per-row constants.
template <int LAST>
__global__ __launch_bounds__(256, 1) void k_gat(const _Float16* __restrict__ hB,
                                                const float* __restrict__ s1g,
                                                const float* __restrict__ s2g,
                                                const unsigned* __restrict__ mask32,
                                                float* __restrict__ outf,
                                                _Float16* __restrict__ oxf,
                                                float* __restrict__ psum, float* __restrict__ pmax) {
    __shared__ float s2s[N];
    __shared__ unsigned msk[128][33];
    __shared__ float wmax[4];
    __shared__ float red1[4][128];
    __shared__ float red2[4][128];
    const int lin = blockIdx.x;                     // 256 blocks
    const int xcd = lin & 7, sl = lin >> 3;         // sl 0..31
    const int b = xcd * 2 + (sl & 1);               // batch pinned to XCD pair
    const int chunk = (sl >> 1) & 7;                // 8 chunks of 128 rows
    const int chalf = sl >> 4;
    const int i0 = chunk * 128;
    const int t = threadIdx.x;
    const int lane = t & 63, w = t >> 6;            // wave w = 32-row group
    const int l31 = lane & 31, hi = lane >> 5;
    const int hi2 = hi * 2, hi8 = hi * 8;

    // ---- stage s2*log2e + mask rows; block-local s2max (scaled domain) ----
    float tm = -INFINITY;
    for (int idx = t; idx < N; idx += 256) {
        float v = s2g[b * N + idx] * LOG2E;
        s2s[idx] = v;
        tm = fmaxf(tm, v);
    }
#pragma unroll
    for (int off = 1; off <= 32; off <<= 1) tm = fmaxf(tm, __shfl_xor(tm, off));
    if (lane == 0) wmax[w] = tm;
#pragma unroll
    for (int pass = 0; pass < 16; pass++) {
        int idx = pass * 256 + t;
        int r = idx >> 5, wd = idx & 31;
        msk[r][wd] = mask32[(size_t)(b * N + i0 + r) * 32 + wd];
    }
    __syncthreads();
    const float s2maxL = fmaxf(fmaxf(wmax[0], wmax[1]), fmaxf(wmax[2], wmax[3]));

    // per-row folded constants: exponent = max(a1c + s2L, fma(ALPHA, s2L, a2c))
    const float s1L = s1g[b * N + i0 + w * 32 + l31] * LOG2E;
    const float tmx = s1L + s2maxL;
    const float mL = fmaxf(tmx, ALPHA * tmx);
    const float a1c = s1L - mL;
    const float a2c = fmaf(ALPHA, s1L, -mL);

    // B-frag pointers: frag (b, ct32 = chalf*4+k4, jt, ks); per-jt stride 1024 halves
    const _Float16* pb[4][2];
#pragma unroll
    for (int k4 = 0; k4 < 4; k4++)
#pragma unroll
        for (int ks = 0; ks < 2; ks++)
            pb[k4][ks] = hB + ((size_t)(b * 8 + chalf * 4 + k4) * 64 + ks) * 512 + lane * 8;

    floatx16 acc[4];
    floatx16 accl;
#pragma unroll
    for (int r = 0; r < 16; r++) accl[r] = 0.f;
#pragma unroll
    for (int k4 = 0; k4 < 4; k4++) acc[k4] = accl;

    half8 ones;
#pragma unroll
    for (int jj = 0; jj < 8; jj++) ones[jj] = (_Float16)1.0f;

    const float* svp = s2s + hi8;
    const unsigned* mr = &msk[w * 32 + l31][0];

    half8 bufA[4][2], bufB[4][2];
#pragma unroll
    for (int k4 = 0; k4 < 4; k4++) {
        bufA[k4][0] = *(const half8*)(pb[k4][0]);
        bufA[k4][1] = *(const half8*)(pb[k4][1]);
    }

#define GAT_STEP(JT, BUF)                                                      \
    do {                                                                       \
        const unsigned m = mr[JT];                                             \
        float4 sa0 = *(const float4*)(svp + (JT) * 32);                        \
        float4 sb0 = *(const float4*)(svp + (JT) * 32 + 4);                    \
        float4 sa1 = *(const float4*)(svp + (JT) * 32 + 16);                   \
        float4 sb1 = *(const float4*)(svp + (JT) * 32 + 20);                   \
        float sv0[8] = {sa0.x, sa0.y, sa0.z, sa0.w, sb0.x, sb0.y, sb0.z, sb0.w};\
        float sv1[8] = {sa1.x, sa1.y, sa1.z, sa1.w, sb1.x, sb1.y, sb1.z, sb1.w};\
        unsigned mq0 = m >> hi2;                                               \
        unsigned mq1 = m >> (4 + hi2);                                         \
        union { _Float16 h[8]; half8 v; } pk0, pk1;                            \
        _Pragma("unroll")                                                      \
        for (int e = 0; e < 8; e++) {                                          \
            const int bp = (e & 3) * 8 + (e >> 2);                             \
            float u0 = a1c + sv0[e];                                           \
            float v0 = fmaf(ALPHA, sv0[e], a2c);                               \
            float w0 = fmaxf(u0, v0);                                          \
            w0 = ((mq0 >> bp) & 1u) ? w0 : -126.f;                             \
            pk0.h[e] = (_Float16)EXP2F(w0);                                    \
            float u1 = a1c + sv1[e];                                           \
            float v1 = fmaf(ALPHA, sv1[e], a2c);                               \
            float w1 = fmaxf(u1, v1);                                          \
            w1 = ((mq1 >> bp) & 1u) ? w1 : -126.f;                             \
            pk1.h[e] = (_Float16)EXP2F(w1);                                    \
        }                                                                      \
        accl = mfma32_f16(pk0.v, ones, accl);                                  \
        _Pragma("unroll")                                                      \
        for (int k4 = 0; k4 < 4; k4++) acc[k4] = mfma32_f16(pk0.v, BUF[k4][0], acc[k4]); \
        accl = mfma32_f16(pk1.v, ones, accl);                                  \
        _Pragma("unroll")                                                      \
        for (int k4 = 0; k4 < 4; k4++) acc[k4] = mfma32_f16(pk1.v, BUF[k4][1], acc[k4]); \
    } while (0)

    for (int jt = 0; jt < 32; jt += 2) {
        {
            const int o = (jt + 1) * 1024;
#pragma unroll
            for (int k4 = 0; k4 < 4; k4++) {
                bufB[k4][0] = *(const half8*)(pb[k4][0] + o);
                bufB[k4][1] = *(const half8*)(pb[k4][1] + o);
            }
        }
        GAT_STEP(jt, bufA);
        if (jt + 2 < 32) {
            const int o = (jt + 2) * 1024;
#pragma unroll
            for (int k4 = 0; k4 < 4; k4++) {
                bufA[k4][0] = *(const half8*)(pb[k4][0] + o);
                bufA[k4][1] = *(const half8*)(pb[k4][1] + o);
            }
        }
        GAT_STEP(jt + 1, bufB);
    }
#undef GAT_STEP

    // accl[reg] = row sum for row (reg&3)+8*(reg>>2)+4*hi — same map as acc
    float invv[16];
#pragma unroll
    for (int r = 0; r < 16; r++) invv[r] = 1.f / accl[r];

    const size_t rowb = (size_t)b * N + i0 + w * 32 + 4 * hi;
    const int colbase = chalf * 128;
#pragma unroll
    for (int k4 = 0; k4 < 4; k4++) {
        const int c = colbase + k4 * 32 + l31;
        float cs = 0.f, cm = -INFINITY;
#pragma unroll
        for (int reg = 0; reg < 16; reg++) {
            const int roff = (reg & 3) + 8 * (reg >> 2);
            float v = fmaxf(acc[k4][reg] * invv[reg], 0.f);
            if (LAST) {
                outf[(rowb + roff) * H + c] = v;
                cs += v; cm = fmaxf(cm, v);
            } else {
                oxf[(rowb + roff) * H + c] = (_Float16)v;
            }
        }
        if (LAST) {
            cs += __shfl_xor(cs, 32);
            cm = fmaxf(cm, __shfl_xor(cm, 32));
            if (hi == 0) { red1[w][k4 * 32 + l31] = cs; red2[w][k4 * 32 + l31] = cm; }
        }
    }
    if (LAST) {
        __syncthreads();
        if (t < 128) {
            float s = red1[0][t] + red1[1][t] + red1[2][t] + red1[3][t];
            float m = fmaxf(fmaxf(red2[0][t], red2[1][t]), fmaxf(red2[2][t], red2[3][t]));
            psum[(b * 8 + chunk) * H + chalf * 128 + t] = s;
            pmax[(b * 8 + chunk) * H + chalf * 128 + t] = m;
        }
    }
}

// ---------------------------------------------------------------------------
// finish mean+max over 8 chunk-partials, then 2-layer MLP -> g[b,:]
__global__ __launch_bounds__(256) void k_pool2(const float* __restrict__ psum,
                                               const float* __restrict__ pmax,
                                               const float* __restrict__ W1, const float* __restrict__ b1,
                                               const float* __restrict__ W2, const float* __restrict__ b2,
                                               float* __restrict__ gout) {
    __shared__ float g_s[H];
    __shared__ float t_s[H];
    const int b = blockIdx.x;
    const int c = threadIdx.x;
    float s = 0.f, m = -INFINITY;
#pragma unroll
    for (int ch = 0; ch < 8; ch++) {
        s += psum[(b * 8 + ch) * H + c];
        m = fmaxf(m, pmax[(b * 8 + ch) * H + c]);
    }
    g_s[c] = s * (1.f / N) + m;
    __syncthreads();
    float a = b1[c];
#pragma unroll 16
    for (int k = 0; k < H; k++) a += g_s[k] * W1[k * H + c];
    t_s[c] = fmaxf(a, 0.f);
    __syncthreads();
    float o = b2[c];
#pragma unroll 16
    for (int k = 0; k < H; k++) o += t_s[k] * W2[k * H + c];
    gout[b * H + c] = o;
}

// ---------------------------------------------------------------------------
extern "C" void kernel_launch(void* const* d_in, const int* in_sizes, int n_in,
                              void* d_out, int out_size, void* d_ws, size_t ws_size,
                              hipStream_t stream) {
    const float* nf    = (const float*)d_in[0];
    const float* adj   = (const float*)d_in[1];
    const float* emb_W = (const float*)d_in[2];
    const float* emb_b = (const float*)d_in[3];
    const float* W0    = (const float*)d_in[4];
    const float* a1_0  = (const float*)d_in[5];
    const float* a2_0  = (const float*)d_in[6];
    const float* W1    = (const float*)d_in[7];
    const float* a1_1  = (const float*)d_in[8];
    const float* a2_1  = (const float*)d_in[9];
    const float* gpW1  = (const float*)d_in[10];
    const float* gpb1  = (const float*)d_in[11];
    const float* gpW2  = (const float*)d_in[12];
    const float* gpb2  = (const float*)d_in[13];

    float* xout = (float*)d_out;
    float* gout = xout + B * N * H;

    char* w = (char*)d_ws;
    _Float16* xf     = (_Float16*)(w);                //  8 MB (layer-1 input)
    _Float16* hB     = (_Float16*)(w + 8388608);      //  8 MB (32x32 B-frag order)
    unsigned* mask32 = (unsigned*)(w + 16777216);     //  2 MB (plane-packed)
    float* s1        = (float*)(w + 18874368);        // 64 KB
    float* s2        = (float*)(w + 18939904);        // 64 KB
    _Float16* wBf    = (_Float16*)(w + 19005440);     // 256 KB (B-frag, 2 layers)
    float* wa1       = (float*)(w + 19267584);
    float* wa2       = (float*)(w + 19269632);
    float* psum      = (float*)(w + 19271680);        // 128 KB
    float* pmax      = (float*)(w + 19533824);        // 128 KB
    _Float16* embf   = (_Float16*)(w + 19795968);     // 32 KB (embW B-frags)

    k_front<<<1059, 256, 0, stream>>>(adj, emb_W, W0, W1,
                                      a1_0, a2_0, a1_1, a2_1,
                                      mask32, wBf, embf, wa1, wa2);

    // layer 0 (embed fused into GEMM)
    k_gemm<1><<<1024, 256, 0, stream>>>(nullptr, nf, embf, emb_b,
                                        wBf, wa1, wa2, hB, s1, s2);
    k_gat<0><<<256, 256, 0, stream>>>(hB, s1, s2, mask32, nullptr, xf,
                                      nullptr, nullptr);

    // layer 1
    k_gemm<0><<<1024, 256, 0, stream>>>(xf, nullptr, nullptr, nullptr,
                                        wBf + 65536, wa1 + H, wa2 + H, hB, s1, s2);
    k_gat<1><<<256, 256, 0, stream>>>(hB, s1, s2, mask32, xout, nullptr,
                                      psum, pmax);

    // pooling MLP
    k_pool2<<<B, 256, 0, stream>>>(psum, pmax, gpW1, gpb1, gpW2, gpb2, gout);
}